// Round 1
// 178.671 us; speedup vs baseline: 1.0702x; 1.0702x over previous
//
#include <hip/hip_runtime.h>
#include <stdint.h>
#include <stddef.h>

// CliffordLinear as one bf16 GEMM:
//   out[b, o*8+l] = sum_{i,k} X[b, i*8+k] * Wt[o*8+l, i*8+k] + bias[o*8+l]
//   Wt[(o,l),(i,k)] = sum_j cayley[j,k,l] * W[o,i,j]
// M=8192, N=2048, K=2048. bf16 MFMA, fp32 accumulate.
//
// R8: port GEMM to the 256x256 8-phase schedule (learn_hip m201 template),
// re-derived as a ring of 4 K-slice slots (slice = 32 wide, 16 KB A + 16 KB B
// per slot, 128 KB LDS total). 8 waves (2Mx4N), acc[8][4], 32 MFMA/slice in
// two 16-MFMA phases. Counted vmcnt(6) once per K-tile (3 half-tiles in
// flight), never 0 in the main loop; setprio(1) around MFMA clusters.
// Stage stream: phase(s,h=0) stages A(s+3); phase(s,h=1) stages B(s+4);
// slot safety from each phase's lgkmcnt(0)+barrier (reads drained before the
// next phase may issue an overwrite of that slot).
// Proven pieces kept from R5/R7: quad-XOR LDS swizzle (measured 0 bank
// conflicts at row-stride-64B), 16x16x32 fragment + epilogue layout, fused
// prep kernel.

typedef __bf16 bf16x8  __attribute__((ext_vector_type(8)));
typedef float  f32x4   __attribute__((ext_vector_type(4)));

#define BM 256
#define BN 256
#define KSLICE 32
#define NSLICES 64              // K=2048 / 32
#define SLOT_ELEMS (256 * 32)   // one slice of A or B: 16 KB

__device__ __forceinline__ void async_copy16(void* lds_dst, const void* g_src) {
    // global -> LDS direct copy, 16B/lane; dest is wave-uniform base, HW
    // scatters lane i to base + i*16.
    __builtin_amdgcn_global_load_lds(
        (__attribute__((address_space(1))) void*)g_src,
        (__attribute__((address_space(3))) void*)lds_dst,
        16, 0, 0);
}

// ---------------- kernel 1: fused prep (cast X -> bf16, fold Cayley) -------
// blocks [0, castBlocks): cast; blocks [castBlocks, ...): fold.
__global__ __launch_bounds__(256) void prep_kernel(
    const float* __restrict__ x, __bf16* __restrict__ Xb, long nx,
    const float* __restrict__ W, const float* __restrict__ cayley,
    __bf16* __restrict__ Wt, int Cin, int Cout, int castBlocks)
{
    __shared__ float Cay[512];
    if ((int)blockIdx.x < castBlocks) {
        long i = ((long)blockIdx.x * 256 + threadIdx.x) * 8;
        if (i + 8 <= nx) {
            const f32x4* p = (const f32x4*)(x + i);
            f32x4 v0 = p[0];
            f32x4 v1 = p[1];
            bf16x8 o;
            o[0] = (__bf16)v0[0]; o[1] = (__bf16)v0[1];
            o[2] = (__bf16)v0[2]; o[3] = (__bf16)v0[3];
            o[4] = (__bf16)v1[0]; o[5] = (__bf16)v1[1];
            o[6] = (__bf16)v1[2]; o[7] = (__bf16)v1[3];
            *(bf16x8*)(Xb + i) = o;
        }
        return;
    }
    // ---- fold: Wt[n][i*8+k] = sum_j C[j,k,l] * W[o,i,j], n = o*8+l
    for (int t = threadIdx.x; t < 512; t += 256) Cay[t] = cayley[t];
    __syncthreads();

    int flat = (blockIdx.x - castBlocks) * 256 + threadIdx.x;  // n*Cin + i
    int total = Cout * 8 * Cin;
    if (flat >= total) return;
    int i = flat % Cin;
    int n = flat / Cin;
    int o = n >> 3, l = n & 7;

    const float* wrow = W + ((size_t)o * Cin + i) * 8;
    float w8[8];
    #pragma unroll
    for (int j = 0; j < 8; ++j) w8[j] = wrow[j];

    bf16x8 outv;
    #pragma unroll
    for (int k = 0; k < 8; ++k) {
        float s = 0.f;
        #pragma unroll
        for (int j = 0; j < 8; ++j) s += Cay[j * 64 + k * 8 + l] * w8[j];
        outv[k] = (__bf16)s;
    }
    *(bf16x8*)(Wt + (size_t)n * (Cin * 8) + i * 8) = outv;
}

// ---------------- kernel 2: bf16 GEMM, C = A * Bt^T + bias ----------------
// A  : [M][K] bf16 (row-major, pre-cast)
// Bt : [N][K] bf16 (row-major)
// C  : [M][N] fp32
//
// LDS: As[4]/Bs[4] ring of K-slice slots, each [256 rows][32 cols] bf16.
// Row = 64 B = 4 groups of 16 B. Physical group p of row r holds GLOBAL
// group p ^ ((r>>1) & 3) (swizzle applied on the staging SOURCE address;
// global_load_lds lane scatter stays linear). Fragment read uses physical
// group quad ^ ((l16>>1) & 3). Measured SQ_LDS_BANK_CONFLICT = 0 (R4/R5).
__global__ __launch_bounds__(512, 2) void gemm_bt_kernel(
    const __bf16* __restrict__ A,
    const __bf16* __restrict__ Bt,
    const float*  __restrict__ bias,
    float* __restrict__ C,
    int M, int N, int K)
{
    __shared__ __align__(16) __bf16 As[4][SLOT_ELEMS];  // 4 x 16 KB
    __shared__ __align__(16) __bf16 Bs[4][SLOT_ELEMS];  // 4 x 16 KB

    const int tid  = threadIdx.x;
    const int wave = tid >> 6;    // 0..7
    const int lane = tid & 63;
    const int quad = lane >> 4;   // 0..3
    const int l16  = lane & 15;   // 0..15

    // --- XCD swizzle: 256 blocks, 8 XCDs; XCD x owns M-tiles [4x,4x+4) x all
    // 8 N-tiles (A-panel 4 MB fits the per-XCD L2). Bijective since 256%8==0.
    const int bid = blockIdx.x;
    const int xcd = bid & 7;
    const int idx = bid >> 3;                 // 0..31
    const int mBase = (xcd * 4 + (idx & 3)) * BM;
    const int nBase = (idx >> 2) * BN;

    // --- staging: one slice (16 KB) = 8 waves x 2 chunks x 1 KB.
    // Wave w, chunk c covers rows 32w+16c .. +15; lane L writes row
    // 32w+16c+(L>>2), physical group L&3, which must hold global group
    // (L&3) ^ ((L>>3)&3)  (= group ^ ((row>>1)&3), row bits from L).
    const int srow = lane >> 2;
    const int sgrp = (lane & 3) ^ ((lane >> 3) & 3);
    const __bf16* gA0 = A  + (size_t)(mBase + wave * 32 +  0 + srow) * K + sgrp * 8;
    const __bf16* gA1 = A  + (size_t)(mBase + wave * 32 + 16 + srow) * K + sgrp * 8;
    const __bf16* gB0 = Bt + (size_t)(nBase + wave * 32 +  0 + srow) * K + sgrp * 8;
    const __bf16* gB1 = Bt + (size_t)(nBase + wave * 32 + 16 + srow) * K + sgrp * 8;
    const int stOff = wave * 1024;  // elements (2 KB per wave per slice)

#define STAGE_A(slot, q) do {                                          \
        async_copy16(&As[slot][stOff      ], gA0 + (size_t)(q) * KSLICE); \
        async_copy16(&As[slot][stOff + 512], gA1 + (size_t)(q) * KSLICE); \
    } while (0)
#define STAGE_B(slot, q) do {                                          \
        async_copy16(&Bs[slot][stOff      ], gB0 + (size_t)(q) * KSLICE); \
        async_copy16(&Bs[slot][stOff + 512], gB1 + (size_t)(q) * KSLICE); \
    } while (0)

    // --- compute: wave (wm,wn) owns a 128x64 sub-tile; 8x4 frags of 16x16.
    const int wm = wave >> 2;     // 0..1
    const int wn = wave & 3;      // 0..3
    const int offq = (quad ^ ((l16 >> 1) & 3)) * 8;     // swizzled frag group
    const int aOff = (wm * 128 + l16) * KSLICE + offq;  // element offset in slot
    const int bOff = (wn * 64  + l16) * KSLICE + offq;

    f32x4 acc[8][4] = {};

    // --- prologue: stage A0,B0,A1,B1,A2,B2,B3 (7 halves, 14 loads/thread).
    // vmcnt(6) leaves {A2,B2,B3} in flight -> slices 0,1 landed. Barrier
    // makes every wave's loads visible before any ds_read.
    STAGE_A(0, 0); STAGE_B(0, 0);
    STAGE_A(1, 1); STAGE_B(1, 1);
    STAGE_A(2, 2); STAGE_B(2, 2);
    STAGE_B(3, 3);
    asm volatile("s_waitcnt vmcnt(6)" ::: "memory");
    __syncthreads();

    // --- main loop: 64 slices x 2 phases. Counted vmcnt(6) at the end of
    // every odd slice (= K-tile boundary) keeps 3 half-tiles in flight;
    // vmcnt(0) only at the final drain (s>=61).
    #pragma unroll 2
    for (int s = 0; s < NSLICES; ++s) {
        const __bf16* pa = &As[s & 3][aOff];
        const __bf16* pb = &Bs[s & 3][bOff];

        // ---- phase h=0: read A-frags m0..3 + all B-frags; stage A(s+3).
        // Target slot (s+3)&3 = (s-1)&3 was last read in the previous phase
        // (its lgkmcnt(0)+barrier drained all waves' reads).
        bf16x8 af0[4], bf[4];
        #pragma unroll
        for (int j = 0; j < 4; ++j) af0[j] = *(const bf16x8*)(pa + j * 512);
        #pragma unroll
        for (int n = 0; n < 4; ++n) bf[n]  = *(const bf16x8*)(pb + n * 512);
        if (s <= 60) STAGE_A((s + 3) & 3, s + 3);
        __builtin_amdgcn_s_barrier();
        asm volatile("s_waitcnt lgkmcnt(0)" ::: "memory");
        __builtin_amdgcn_s_setprio(1);
        #pragma unroll
        for (int j = 0; j < 4; ++j)
            #pragma unroll
            for (int n = 0; n < 4; ++n)
                acc[j][n] = __builtin_amdgcn_mfma_f32_16x16x32_bf16(
                    af0[j], bf[n], acc[j][n], 0, 0, 0);
        __builtin_amdgcn_s_setprio(0);
        __builtin_amdgcn_s_barrier();

        // ---- phase h=1: read A-frags m4..7 (B-frags reused); stage B(s+4).
        // Target slot s&3: this slice's B was last read in phase h=0 above.
        bf16x8 af1[4];
        #pragma unroll
        for (int j = 0; j < 4; ++j) af1[j] = *(const bf16x8*)(pa + (4 + j) * 512);
        if (s <= 59) STAGE_B(s & 3, s + 4);
        __builtin_amdgcn_s_barrier();
        asm volatile("s_waitcnt lgkmcnt(0)" ::: "memory");
        __builtin_amdgcn_s_setprio(1);
        #pragma unroll
        for (int j = 0; j < 4; ++j)
            #pragma unroll
            for (int n = 0; n < 4; ++n)
                acc[4 + j][n] = __builtin_amdgcn_mfma_f32_16x16x32_bf16(
                    af1[j], bf[n], acc[4 + j][n], 0, 0, 0);
        __builtin_amdgcn_s_setprio(0);
        if (s & 1) {
            // K-tile boundary: next 2 slices' data must be landed. Steady
            // state leaves exactly {B(s+1),A(s+1),B(s+2)} = 6 loads in
            // flight; final boundary (s=61) drains everything.
            if (s >= 61) asm volatile("s_waitcnt vmcnt(0)" ::: "memory");
            else         asm volatile("s_waitcnt vmcnt(6)" ::: "memory");
        }
        __builtin_amdgcn_s_barrier();
    }

#undef STAGE_A
#undef STAGE_B

    // --- epilogue: C/D layout col = lane&15, row = quad*4 + reg
    float bv[4];
    #pragma unroll
    for (int n = 0; n < 4; ++n)
        bv[n] = bias[nBase + wn * 64 + n * 16 + l16];

    #pragma unroll
    for (int m = 0; m < 8; ++m) {
        #pragma unroll
        for (int n = 0; n < 4; ++n) {
            const int col = nBase + wn * 64 + n * 16 + l16;
            #pragma unroll
            for (int r = 0; r < 4; ++r) {
                const int row = mBase + wm * 128 + m * 16 + quad * 4 + r;
                C[(size_t)row * N + col] = acc[m][n][r] + bv[n];
            }
        }
    }
}

extern "C" void kernel_launch(void* const* d_in, const int* in_sizes, int n_in,
                              void* d_out, int out_size, void* d_ws, size_t ws_size,
                              hipStream_t stream) {
    const float* x      = (const float*)d_in[0];  // [B][Cin][8]
    const float* weight = (const float*)d_in[1];  // [Cout][Cin][8]
    const float* bias   = (const float*)d_in[2];  // [Cout][8]
    const float* cayley = (const float*)d_in[3];  // [8][8][8]
    float* out = (float*)d_out;                   // [B][Cout][8]

    const int Cout = in_sizes[2] / 8;
    const int Cin  = in_sizes[1] / (Cout * 8);
    const int Bm   = in_sizes[0] / (Cin * 8);
    const int M = Bm;          // 8192
    const int N = Cout * 8;    // 2048
    const int K = Cin * 8;     // 2048

    __bf16* Xb = (__bf16*)d_ws;                               // M*K bf16 = 32 MB
    __bf16* Wt = (__bf16*)((char*)d_ws + (size_t)M * K * 2);  // N*K bf16 = 8 MB

    // 1) fused prep: cast X + fold Cayley into Wt, one dispatch
    long nx = (long)M * K;
    int castBlocks = (int)(nx / 8 / 256);               // nx divisible by 2048
    int foldBlocks = (N * Cin + 255) / 256;
    prep_kernel<<<castBlocks + foldBlocks, 256, 0, stream>>>(
        x, Xb, nx, weight, cayley, Wt, Cin, Cout, castBlocks);

    // 2) GEMM: 256x256 tiles, 32 x 8 = 256 blocks, 512 threads (8 waves)
    int grid = (M / BM) * (N / BN);
    gemm_bt_kernel<<<grid, 512, 0, stream>>>(Xb, Wt, bias, out, M, N, K);
}

// Round 2
// 176.359 us; speedup vs baseline: 1.0842x; 1.0131x over previous
//
#include <hip/hip_runtime.h>
#include <stdint.h>
#include <stddef.h>

// CliffordLinear as one bf16 GEMM:
//   out[b, o*8+l] = sum_{i,k} X[b, i*8+k] * Wt[o*8+l, i*8+k] + bias[o*8+l]
//   Wt[(o,l),(i,k)] = sum_j cayley[j,k,l] * W[o,i,j]
// M=8192, N=2048, K=2048. bf16 MFMA, fp32 accumulate.
//
// R9: break the LDS-read / MFMA serialization that capped R8 at MfmaUtil 37%.
// Each window now issues the NEXT window's ds_reads (register ping-pong
// af0A/bfA <-> af0B/bfB) before its own MFMA cluster; the compiler's
// automatic counted lgkmcnt (4/8) lets those reads fly DURING the 16-MFMA
// cluster, so the LDS pipe and matrix pipe run concurrently instead of
// alternating. One barrier per window (WAR safety: all reads of a slot
// complete before that window's end barrier via lgkmcnt-before-MFMA; the
// earliest overwrite of the slot is >= 1 barrier later). vmcnt(8) after the
// h0 MFMA guarantees slice s+1's staging landed before the h1 prefetch reads
// it; prologue (A0,B0,A1,B1,A2,B2,B3 + vmcnt(10)) establishes the invariant.
// 4-slice unrolled body makes ring-slot indices compile-time (ds base+imm).
// Kept from R8: 4-slot ring (32 KB/slice, 128 KB LDS), 8 waves 2Mx4N,
// quad-XOR swizzle (0 conflicts), vmcnt never 0 in the loop, setprio, XCD
// swizzle, fused prep kernel.

typedef __bf16 bf16x8  __attribute__((ext_vector_type(8)));
typedef float  f32x4   __attribute__((ext_vector_type(4)));

#define BM 256
#define BN 256
#define KSLICE 32
#define NSLICES 64              // K=2048 / 32
#define SLOT_ELEMS (256 * 32)   // one slice of A or B: 16 KB

__device__ __forceinline__ void async_copy16(void* lds_dst, const void* g_src) {
    __builtin_amdgcn_global_load_lds(
        (__attribute__((address_space(1))) void*)g_src,
        (__attribute__((address_space(3))) void*)lds_dst,
        16, 0, 0);
}

// ---------------- kernel 1: fused prep (cast X -> bf16, fold Cayley) -------
__global__ __launch_bounds__(256) void prep_kernel(
    const float* __restrict__ x, __bf16* __restrict__ Xb, long nx,
    const float* __restrict__ W, const float* __restrict__ cayley,
    __bf16* __restrict__ Wt, int Cin, int Cout, int castBlocks)
{
    __shared__ float Cay[512];
    if ((int)blockIdx.x < castBlocks) {
        long i = ((long)blockIdx.x * 256 + threadIdx.x) * 8;
        if (i + 8 <= nx) {
            const f32x4* p = (const f32x4*)(x + i);
            f32x4 v0 = p[0];
            f32x4 v1 = p[1];
            bf16x8 o;
            o[0] = (__bf16)v0[0]; o[1] = (__bf16)v0[1];
            o[2] = (__bf16)v0[2]; o[3] = (__bf16)v0[3];
            o[4] = (__bf16)v1[0]; o[5] = (__bf16)v1[1];
            o[6] = (__bf16)v1[2]; o[7] = (__bf16)v1[3];
            *(bf16x8*)(Xb + i) = o;
        }
        return;
    }
    for (int t = threadIdx.x; t < 512; t += 256) Cay[t] = cayley[t];
    __syncthreads();

    int flat = (blockIdx.x - castBlocks) * 256 + threadIdx.x;  // n*Cin + i
    int total = Cout * 8 * Cin;
    if (flat >= total) return;
    int i = flat % Cin;
    int n = flat / Cin;
    int o = n >> 3, l = n & 7;

    const float* wrow = W + ((size_t)o * Cin + i) * 8;
    float w8[8];
    #pragma unroll
    for (int j = 0; j < 8; ++j) w8[j] = wrow[j];

    bf16x8 outv;
    #pragma unroll
    for (int k = 0; k < 8; ++k) {
        float s = 0.f;
        #pragma unroll
        for (int j = 0; j < 8; ++j) s += Cay[j * 64 + k * 8 + l] * w8[j];
        outv[k] = (__bf16)s;
    }
    *(bf16x8*)(Wt + (size_t)n * (Cin * 8) + i * 8) = outv;
}

// ---------------- kernel 2: bf16 GEMM, C = A * Bt^T + bias ----------------
__global__ __launch_bounds__(512, 2) void gemm_bt_kernel(
    const __bf16* __restrict__ A,
    const __bf16* __restrict__ Bt,
    const float*  __restrict__ bias,
    float* __restrict__ C,
    int M, int N, int K)
{
    __shared__ __align__(16) __bf16 As[4][SLOT_ELEMS];  // 4 x 16 KB
    __shared__ __align__(16) __bf16 Bs[4][SLOT_ELEMS];  // 4 x 16 KB

    const int tid  = threadIdx.x;
    const int wave = tid >> 6;    // 0..7
    const int lane = tid & 63;
    const int quad = lane >> 4;   // 0..3
    const int l16  = lane & 15;   // 0..15

    // --- XCD swizzle: 256 blocks, 8 XCDs; bijective since 256%8==0.
    const int bid = blockIdx.x;
    const int xcd = bid & 7;
    const int idx = bid >> 3;                 // 0..31
    const int mBase = (xcd * 4 + (idx & 3)) * BM;
    const int nBase = (idx >> 2) * BN;

    // --- staging addresses (quad-XOR source swizzle; LDS dest stays linear)
    const int srow = lane >> 2;
    const int sgrp = (lane & 3) ^ ((lane >> 3) & 3);
    const __bf16* gA0 = A  + (size_t)(mBase + wave * 32 +  0 + srow) * K + sgrp * 8;
    const __bf16* gA1 = A  + (size_t)(mBase + wave * 32 + 16 + srow) * K + sgrp * 8;
    const __bf16* gB0 = Bt + (size_t)(nBase + wave * 32 +  0 + srow) * K + sgrp * 8;
    const __bf16* gB1 = Bt + (size_t)(nBase + wave * 32 + 16 + srow) * K + sgrp * 8;
    const int stOff = wave * 1024;  // elements (2 KB per wave per slice)

#define STAGE_A(slot, q) do {                                             \
        async_copy16(&As[slot][stOff      ], gA0 + (size_t)(q) * KSLICE); \
        async_copy16(&As[slot][stOff + 512], gA1 + (size_t)(q) * KSLICE); \
    } while (0)
#define STAGE_B(slot, q) do {                                             \
        async_copy16(&Bs[slot][stOff      ], gB0 + (size_t)(q) * KSLICE); \
        async_copy16(&Bs[slot][stOff + 512], gB1 + (size_t)(q) * KSLICE); \
    } while (0)

    // --- compute: wave (wm,wn) owns a 128x64 sub-tile; 8x4 frags of 16x16.
    const int wm = wave >> 2;     // 0..1
    const int wn = wave & 3;      // 0..3
    const int offq = (quad ^ ((l16 >> 1) & 3)) * 8;
    const __bf16* paBase = &As[0][(wm * 128 + l16) * KSLICE + offq];
    const __bf16* pbBase = &Bs[0][(wn * 64  + l16) * KSLICE + offq];

    f32x4 acc[8][4] = {};
    bf16x8 af0A[4], bfA[4], af0B[4], bfB[4], af1[4];

    // --- prologue: stage A0,B0,A1,B1,A2,B2,B3 (matches steady interleave).
    // vmcnt(10) leaves the last 5 stages {A1,B1,A2,B2,B3} in flight ->
    // A0,B0 landed. Barrier, then pre-read slice-0 frags into set A.
    STAGE_A(0, 0); STAGE_B(0, 0);
    STAGE_A(1, 1); STAGE_B(1, 1);
    STAGE_A(2, 2); STAGE_B(2, 2);
    STAGE_B(3, 3);
    asm volatile("s_waitcnt vmcnt(10)" ::: "memory");
    __builtin_amdgcn_s_barrier();

    #pragma unroll
    for (int j = 0; j < 4; ++j)
        af0A[j] = *(const bf16x8*)(paBase + j * 512);
    #pragma unroll
    for (int j = 0; j < 4; ++j)
        bfA[j]  = *(const bf16x8*)(pbBase + j * 512);

    // One slice = two windows.
    //  h0: read af1 (A m4-7, slot c) | stage A(s+3) | MFMA m0-3 on (AF0,BF)
    //      | vmcnt(8)  -> A(s+1),B(s+1) landed | barrier
    //  h1: read af0/bf of slice s+1 (slot n_) into (NAF0,NBF) | stage B(s+4)
    //      | MFMA m4-7 on (af1,BF) | barrier
    // Compiler inserts counted lgkmcnt before each MFMA cluster -> the 8 (or
    // 4) just-issued reads stay in flight during the MFMA cluster.
#define SLICE_BODY(s_, c_, n_, AF0, BF, NAF0, NBF, DOA, DOB, DOPF)             \
    do {                                                                       \
        _Pragma("unroll")                                                      \
        for (int j = 0; j < 4; ++j)                                            \
            af1[j] = *(const bf16x8*)(paBase + (c_) * SLOT_ELEMS + (4 + j) * 512); \
        if (DOA) STAGE_A(((s_) + 3) & 3, (s_) + 3);                            \
        __builtin_amdgcn_s_setprio(1);                                         \
        _Pragma("unroll")                                                      \
        for (int j = 0; j < 4; ++j)                                            \
            _Pragma("unroll")                                                  \
            for (int n = 0; n < 4; ++n)                                        \
                acc[j][n] = __builtin_amdgcn_mfma_f32_16x16x32_bf16(           \
                    AF0[j], BF[n], acc[j][n], 0, 0, 0);                        \
        __builtin_amdgcn_s_setprio(0);                                         \
        asm volatile("s_waitcnt vmcnt(8)" ::: "memory");                       \
        __builtin_amdgcn_s_barrier();                                          \
        if (DOPF) {                                                            \
            _Pragma("unroll")                                                  \
            for (int j = 0; j < 4; ++j)                                        \
                NAF0[j] = *(const bf16x8*)(paBase + (n_) * SLOT_ELEMS + j * 512); \
            _Pragma("unroll")                                                  \
            for (int j = 0; j < 4; ++j)                                        \
                NBF[j] = *(const bf16x8*)(pbBase + (n_) * SLOT_ELEMS + j * 512); \
        }                                                                      \
        if (DOB) STAGE_B((s_) & 3, (s_) + 4);                                  \
        __builtin_amdgcn_s_setprio(1);                                         \
        _Pragma("unroll")                                                      \
        for (int j = 0; j < 4; ++j)                                            \
            _Pragma("unroll")                                                  \
            for (int n = 0; n < 4; ++n)                                        \
                acc[4 + j][n] = __builtin_amdgcn_mfma_f32_16x16x32_bf16(       \
                    af1[j], BF[n], acc[4 + j][n], 0, 0, 0);                    \
        __builtin_amdgcn_s_setprio(0);                                         \
        __builtin_amdgcn_s_barrier();                                          \
    } while (0)

    // --- main loop: 60 slices, all guards compile-time true.
    #pragma unroll 1
    for (int s4 = 0; s4 < 15; ++s4) {
        const int s = s4 * 4;
        SLICE_BODY(s + 0, 0, 1, af0A, bfA, af0B, bfB, true, true, true);
        SLICE_BODY(s + 1, 1, 2, af0B, bfB, af0A, bfA, true, true, true);
        SLICE_BODY(s + 2, 2, 3, af0A, bfA, af0B, bfB, true, true, true);
        SLICE_BODY(s + 3, 3, 0, af0B, bfB, af0A, bfA, true, true, true);
    }
    // --- tail: slices 60..63. A-stage only at 60 (A63); no B-stages;
    // prefetch off at 63.
    SLICE_BODY(60, 0, 1, af0A, bfA, af0B, bfB, true,  false, true);
    SLICE_BODY(61, 1, 2, af0B, bfB, af0A, bfA, false, false, true);
    SLICE_BODY(62, 2, 3, af0A, bfA, af0B, bfB, false, false, true);
    SLICE_BODY(63, 3, 0, af0B, bfB, af0A, bfA, false, false, false);
    asm volatile("s_waitcnt vmcnt(0)" ::: "memory");

#undef SLICE_BODY
#undef STAGE_A
#undef STAGE_B

    // --- epilogue: C/D layout col = lane&15, row = quad*4 + reg
    float bv[4];
    #pragma unroll
    for (int n = 0; n < 4; ++n)
        bv[n] = bias[nBase + wn * 64 + n * 16 + l16];

    #pragma unroll
    for (int m = 0; m < 8; ++m) {
        #pragma unroll
        for (int n = 0; n < 4; ++n) {
            const int col = nBase + wn * 64 + n * 16 + l16;
            #pragma unroll
            for (int r = 0; r < 4; ++r) {
                const int row = mBase + wm * 128 + m * 16 + quad * 4 + r;
                C[(size_t)row * N + col] = acc[m][n][r] + bv[n];
            }
        }
    }
}

extern "C" void kernel_launch(void* const* d_in, const int* in_sizes, int n_in,
                              void* d_out, int out_size, void* d_ws, size_t ws_size,
                              hipStream_t stream) {
    const float* x      = (const float*)d_in[0];  // [B][Cin][8]
    const float* weight = (const float*)d_in[1];  // [Cout][Cin][8]
    const float* bias   = (const float*)d_in[2];  // [Cout][8]
    const float* cayley = (const float*)d_in[3];  // [8][8][8]
    float* out = (float*)d_out;                   // [B][Cout][8]

    const int Cout = in_sizes[2] / 8;
    const int Cin  = in_sizes[1] / (Cout * 8);
    const int Bm   = in_sizes[0] / (Cin * 8);
    const int M = Bm;          // 8192
    const int N = Cout * 8;    // 2048
    const int K = Cin * 8;     // 2048

    __bf16* Xb = (__bf16*)d_ws;                               // M*K bf16 = 32 MB
    __bf16* Wt = (__bf16*)((char*)d_ws + (size_t)M * K * 2);  // N*K bf16 = 8 MB

    long nx = (long)M * K;
    int castBlocks = (int)(nx / 8 / 256);               // nx divisible by 2048
    int foldBlocks = (N * Cin + 255) / 256;
    prep_kernel<<<castBlocks + foldBlocks, 256, 0, stream>>>(
        x, Xb, nx, weight, cayley, Wt, Cin, Cout, castBlocks);

    int grid = (M / BM) * (N / BN);
    gemm_bt_kernel<<<grid, 512, 0, stream>>>(Xb, Wt, bias, out, M, N, K);
}